// Round 2
// 87.898 us; speedup vs baseline: 1.0263x; 1.0263x over previous
//
#include <hip/hip_runtime.h>

// S4D, single-kernel (R10b = R10 + __align__(16) on the shared block; the
// R10 bench failed on container infra with no counters, so this is a retry).
//
//  y[c*64+t] = sum_j k[t-j]*x[c*64+j]              (lower-tri Toeplitz, local)
//            + Re( sum_n Ceff2_n w_n^{t+1} S_n[c] ) (carry from prior chunks)
//  S_n[c]    = w^64 * S_n[c-1] + V_n[c-1],  V_n[c] = sum_j w_n^{63-j} x[c*64+j]
//
//  R10: the 5 per-h bf16 operator matrices (W1r/W1i for phase A, TL/W2r/W2i
//  for phase C) are computed DIRECTLY IN LDS in a new phase 0 — the separate
//  s4d_prep kernel (1 wave/SIMD, latency-bound transcendentals) and its
//  10.6 MB HBM write + ~20 MB re-read are gone. LDS lifetime plan (bytes):
//    [0,17160)      qr table (phase 0)   } dies at barrier #3
//    [17160,34320)  qi table (phase 0)   }
//    [0,34816)      packed V (phase A out -> phase B in)
//    [0,36864)      S planes spr/spi (phase B out -> phase C in; clobbers
//                   only the first 2 KB of w1r, which is dead after phase A)
//    [34816,53248)  W1r/W1i (phase 0 out -> phase A in; disjoint from vpk!)
//    [53248,80896)  wreg: TL / W2r / W2i (phase 0 out -> phase C in,
//                   same 0/4608/9216 ushort offsets as R9 — phase C untouched)
//    [80896,81408)  eLDS  (w^64 per n, replaces global Earr)
//    [81408,81664)  klds  (k[t], 64 floats)
//  81664 B <= 81920 B  ->  still 2 blocks/CU (8 waves/CU during phase 0,
//  vs prep's 4 waves/CU). x is loaded as raw float4 at kernel top so HBM
//  latency hides under phase-0 transcendentals; bf16 hi/lo split happens
//  after phase 0c. k-sum parallelized 4x via __shfl_xor (prep had a serial
//  64-iter loop on wave 0). All bf16 rounding paths bit-identical to R9.

#define B_ 8
#define H_ 256
#define N_ 64
#define L_ 2048
#define Q_ 64
#define NC_ 32
#define COLS_ 128
#define PKSTR_ 68      // packed V row stride (uints)
#define PLSTR_ 72      // W/plane row stride (ushorts); 144 B rows, 16B-aligned

typedef __attribute__((ext_vector_type(8))) short bf16x8;
typedef __attribute__((ext_vector_type(4))) float f32x4;

#if defined(__has_builtin)
#  if __has_builtin(__builtin_amdgcn_cvt_pk_bf16_f32)
#    define HAVE_CVT_PK 1
#  endif
#endif

__device__ __forceinline__ unsigned short bf16_rne(float f) {
    unsigned int u = __float_as_uint(f);
    u += 0x7FFF + ((u >> 16) & 1);
    return (unsigned short)(u >> 16);
}
// pack two floats to bf16x2 (a -> low, b -> high), RNE
__device__ __forceinline__ unsigned int pack_bf16x2(float a, float b) {
#ifdef HAVE_CVT_PK
    typedef __bf16 bf16v2 __attribute__((ext_vector_type(2)));
    bf16v2 p = __builtin_amdgcn_cvt_pk_bf16_f32(a, b);
    return __builtin_bit_cast(unsigned int, p);
#else
    unsigned int ua = __float_as_uint(a);
    ua += 0x7FFF + ((ua >> 16) & 1);
    unsigned int ub = __float_as_uint(b);
    ub += 0x7FFF + ((ub >> 16) & 1);
    return (ua >> 16) | (ub & 0xFFFF0000u);
#endif
}

__global__ __launch_bounds__(256, 2) void s4d_one(
    const float* __restrict__ x,
    const float* __restrict__ A_real, const float* __restrict__ A_imag,
    const float* __restrict__ Bmat, const float* __restrict__ Cmat,
    const float* __restrict__ inv_dt,
    float* __restrict__ out)
{
    __shared__ __align__(16) char smem[81664];
    float*          qr_l = (float*)smem;                       // 65x66
    float*          qi_l = (float*)(smem + 17160);             // 65x66
    unsigned int*   vpk  = (unsigned int*)smem;                // 128x68
    unsigned short* spr  = (unsigned short*)smem;              // 128x72
    unsigned short* spi  = (unsigned short*)(smem + 18432);    // 128x72
    unsigned short* w1r  = (unsigned short*)(smem + 34816);    // 64x72
    unsigned short* w1i  = (unsigned short*)(smem + 44032);    // 64x72
    unsigned short* wreg = (unsigned short*)(smem + 53248);    // 3x(64x72)
    float2*         eLDS = (float2*)(smem + 80896);            // w^64 per n
    float*          klds = (float*)(smem + 81408);             // k[0..63]

    const int h     = blockIdx.x >> 1;
    const int bhalf = blockIdx.x & 1;
    const int tid   = threadIdx.x;
    const int lane  = tid & 63;
    const int wv    = tid >> 6;
    const int colw  = wv * 32;
    const int l15   = lane & 15;
    const int quad  = lane >> 4;

    // ---- issue x loads FIRST (raw); latency hides under phase-0 ALU ----
    float4 xraw[2][2][2];
    #pragma unroll
    for (int mt = 0; mt < 2; ++mt) {
        const int bc = colw + mt * 16 + l15;
        const int b  = bhalf * 4 + (bc >> 5);
        const int c  = bc & 31;
        const float* xp = x + ((size_t)(b * H_ + h)) * L_ + c * Q_;
        #pragma unroll
        for (int kk = 0; kk < 2; ++kk) {
            const int j0 = kk * 32 + quad * 8;
            xraw[mt][kk][0] = *(const float4*)(xp + j0);
            xraw[mt][kk][1] = *(const float4*)(xp + j0 + 4);
        }
    }

    // ================= phase 0a: params, W1 -> LDS, q tables -> LDS ======
    const int n   = tid >> 2;           // 0..63
    const int blk = tid & 3;            // 16-element column block
    const int hn  = h * N_ + n;
    {
        const float Ar = -expf(A_real[hn]);     // A = -exp(A_real) - i*A_imag
        const float Ai = -A_imag[hn];
        const float dtv = expf(inv_dt[h]);
        const float dr = dtv * Ar;
        const float di = dtv * Ai;
        const float ew = expf(dr);
        float sdi, cdi;
        sincosf(di, &sdi, &cdi);
        const float wr = ew * cdi;              // w = exp(dt*A)
        const float wi = ew * sdi;
        const float em1r = wr - 1.0f;           // (w-1)/A
        const float em1i = wi;
        const float invden = 1.0f / (Ar * Ar + Ai * Ai);
        const float tr = (em1r * Ar + em1i * Ai) * invden;
        const float ti = (em1i * Ar - em1r * Ai) * invden;
        const float br = Bmat[2 * hn], bi = Bmat[2 * hn + 1];
        const float cr = Cmat[2 * hn], ci = Cmat[2 * hn + 1];
        const float bcr = br * cr - bi * ci;
        const float bci = br * ci + bi * cr;
        const float Cr = 2.0f * (bcr * tr - bci * ti);   // Ceff2
        const float Ci = 2.0f * (bcr * ti + bci * tr);

        // ---- W1[n][j] = w^(63-j), j in [16*blk, 16*blk+16) ----
        {
            const int m0 = 48 - 16 * blk;
            const float e0 = expf((float)m0 * dr);
            float s0, c0;
            sincosf((float)m0 * di, &s0, &c0);
            float pr = e0 * c0, pi = e0 * s0;    // w^m0
            union { unsigned short u16[16]; uint4 q[2]; } tr_, ti_;
            #pragma unroll
            for (int i = 0; i < 16; ++i) {       // m = m0+i -> local j = 15-i
                tr_.u16[15 - i] = bf16_rne(pr);
                ti_.u16[15 - i] = bf16_rne(pi);
                const float npr = pr * wr - pi * wi;
                pi = pr * wi + pi * wr;
                pr = npr;
            }
            uint4* d0 = (uint4*)(w1r + n * PLSTR_ + blk * 16);
            d0[0] = tr_.q[0]; d0[1] = tr_.q[1];
            uint4* d1 = (uint4*)(w1i + n * PLSTR_ + blk * 16);
            d1[0] = ti_.q[0]; d1[1] = ti_.q[1];
        }
        // ---- q table: q[m][n] = Ceff2 * w^m, m partitioned over blk ----
        {
            const int m0   = blk * 17;
            const int mcnt = (blk == 3) ? 14 : 17;
            const float e0 = expf((float)m0 * dr);
            float s0, c0;
            sincosf((float)m0 * di, &s0, &c0);
            float pr = e0 * c0, pi = e0 * s0;    // w^m0
            for (int i = 0; i < mcnt; ++i) {
                const int m = m0 + i;
                qr_l[m * 66 + n] = Cr * pr - Ci * pi;
                qi_l[m * 66 + n] = Cr * pi + Ci * pr;
                const float npr = pr * wr - pi * wi;
                pi = pr * wi + pi * wr;
                pr = npr;
            }
        }
    }
    __syncthreads();

    // ======= phase 0b: k[t] = sum_n qr[t][n] (shfl tree) + E = w^64 ======
    {
        const int t = tid >> 2;
        float s = 0.0f;
        #pragma unroll
        for (int i = 0; i < 16; ++i) s += qr_l[t * 66 + blk * 16 + i];
        s += __shfl_xor(s, 1);
        s += __shfl_xor(s, 2);
        if (blk == 0) klds[t] = s;
    }
    if (tid < 64) {
        const int hn2 = h * N_ + tid;
        const float Ar2 = -expf(A_real[hn2]);
        const float Ai2 = -A_imag[hn2];
        const float dtv = expf(inv_dt[h]);
        const float e64 = expf(64.0f * dtv * Ar2);
        float s64, c64;
        sincosf(64.0f * dtv * Ai2, &s64, &c64);
        eLDS[tid] = make_float2(e64 * c64, e64 * s64);
    }
    __syncthreads();

    // ======= phase 0c: TL[t][j] = (j<=t)?k[t-j]:0 ; W2 from q[t+1] =======
    {
        const int t = tid >> 2;
        union { unsigned short u16[16]; uint4 q[2]; } a_, b_;
        #pragma unroll
        for (int i = 0; i < 16; ++i) {
            const int j = blk * 16 + i;
            const int d = t - j;
            a_.u16[i] = bf16_rne(d >= 0 ? klds[d >= 0 ? d : 0] : 0.0f);
        }
        uint4* dtl = (uint4*)(wreg + t * PLSTR_ + blk * 16);
        dtl[0] = a_.q[0]; dtl[1] = a_.q[1];

        #pragma unroll
        for (int i = 0; i < 16; ++i) {
            const int nn = blk * 16 + i;
            a_.u16[i] = bf16_rne(qr_l[(t + 1) * 66 + nn]);     // Re(Ceff2 w^{t+1})
            b_.u16[i] = bf16_rne(-qi_l[(t + 1) * 66 + nn]);    // -Im(...)
        }
        uint4* d2r = (uint4*)(wreg + 4608 + t * PLSTR_ + blk * 16);
        d2r[0] = a_.q[0]; d2r[1] = a_.q[1];
        uint4* d2i = (uint4*)(wreg + 9216 + t * PLSTR_ + blk * 16);
        d2i[0] = b_.q[0]; d2i[1] = b_.q[1];
    }

    // ---- convert x raw -> bf16 hi/lo fragments (no LDS; overlaps 0c) ----
    bf16x8 xhi[2][2], xlo[2][2];
    #pragma unroll
    for (int mt = 0; mt < 2; ++mt)
        #pragma unroll
        for (int kk = 0; kk < 2; ++kk) {
            const float4 f0 = xraw[mt][kk][0];
            const float4 f1 = xraw[mt][kk][1];
            float f[8] = {f0.x, f0.y, f0.z, f0.w, f1.x, f1.y, f1.z, f1.w};
            union { unsigned int u[4]; bf16x8 v; } hi, lo;
            #pragma unroll
            for (int p = 0; p < 4; ++p) {
                const unsigned int hp = pack_bf16x2(f[2 * p], f[2 * p + 1]);
                hi.u[p] = hp;
                const float h0 = __uint_as_float(hp << 16);
                const float h1 = __uint_as_float(hp & 0xFFFF0000u);
                lo.u[p] = pack_bf16x2(f[2 * p] - h0, f[2 * p + 1] - h1);
            }
            xhi[mt][kk] = hi.v;
            xlo[mt][kk] = lo.v;
        }

    // ---- E = w^64 for n = lane ----
    const float2 E = eLDS[lane];
    const float Er = E.x, Ei = E.y;

    __syncthreads();   // W1/TL/W2 staged; q tables die here

    // ==== phase A: V[(b,c)][n] = X * W1^T (complex) -> packed LDS ========
    // (W1 at [34816,53248) is disjoint from vpk [0,34816): no extra barrier)
    {
        f32x4 accr[2][4], acci[2][4];
        #pragma unroll
        for (int a = 0; a < 2; ++a)
            #pragma unroll
            for (int b = 0; b < 4; ++b) { accr[a][b] = (f32x4)0.0f; acci[a][b] = (f32x4)0.0f; }

        #pragma unroll
        for (int nt = 0; nt < 4; ++nt) {
            const int nn = nt * 16 + l15;
            bf16x8 brf[2], bif[2];
            #pragma unroll
            for (int kk = 0; kk < 2; ++kk) {
                const int j0 = kk * 32 + quad * 8;
                brf[kk] = *(const bf16x8*)(w1r + nn * PLSTR_ + j0);
                bif[kk] = *(const bf16x8*)(w1i + nn * PLSTR_ + j0);
            }
            #pragma unroll
            for (int mt = 0; mt < 2; ++mt)
                #pragma unroll
                for (int kk = 0; kk < 2; ++kk) {
                    accr[mt][nt] = __builtin_amdgcn_mfma_f32_16x16x32_bf16(
                        xhi[mt][kk], brf[kk], accr[mt][nt], 0, 0, 0);
                    acci[mt][nt] = __builtin_amdgcn_mfma_f32_16x16x32_bf16(
                        xhi[mt][kk], bif[kk], acci[mt][nt], 0, 0, 0);
                }
        }

        // D layout: row=(quad*4+r) -> bc, col=l15 -> n
        #pragma unroll
        for (int mt = 0; mt < 2; ++mt)
            #pragma unroll
            for (int nt = 0; nt < 4; ++nt)
                #pragma unroll
                for (int r = 0; r < 4; ++r) {
                    const int bc = colw + mt * 16 + quad * 4 + r;
                    const int nn = nt * 16 + l15;
                    vpk[bc * PKSTR_ + nn] =
                        pack_bf16x2(accr[mt][nt][r], acci[mt][nt][r]);
                }
    }
    __syncthreads();

    // ==== phase B: prefetch V -> barrier -> scan -> S planes =============
    {
        unsigned int vv[NC_];
        const unsigned int* vp = &vpk[(wv * NC_) * PKSTR_ + lane];
        #pragma unroll
        for (int c = 0; c < NC_; ++c) vv[c] = vp[c * PKSTR_];
        __syncthreads();                       // packed-V lifetime ends

        float sr = 0.0f, si = 0.0f;
        unsigned short* pr = &spr[(wv * NC_) * PLSTR_ + lane];
        unsigned short* pi = &spi[(wv * NC_) * PLSTR_ + lane];
        #pragma unroll
        for (int c = 0; c < NC_; ++c) {
            const float vr = __uint_as_float(vv[c] << 16);
            const float vi = __uint_as_float(vv[c] & 0xFFFF0000u);
            const unsigned int sp2 = pack_bf16x2(sr, si);  // entering state
            pr[c * PLSTR_] = (unsigned short)(sp2 & 0xFFFFu);
            pi[c * PLSTR_] = (unsigned short)(sp2 >> 16);
            const float nsr = fmaf(Er, sr, fmaf(-Ei, si, vr));
            si = fmaf(Ei, sr, fmaf(Er, si, vi));
            sr = nsr;
        }
    }
    __syncthreads();

    // ==== phase C: y = Xhi*TL + Xlo*TL + Sr*W2r + Si*W2i, relu ===========
    {
        bf16x8 sr8[2][2], si8[2][2];
        #pragma unroll
        for (int mt = 0; mt < 2; ++mt) {
            const int bc = colw + mt * 16 + l15;
            #pragma unroll
            for (int kk = 0; kk < 2; ++kk) {
                const int j0 = kk * 32 + quad * 8;
                sr8[mt][kk] = *(const bf16x8*)(&spr[bc * PLSTR_ + j0]);
                si8[mt][kk] = *(const bf16x8*)(&spi[bc * PLSTR_ + j0]);
            }
        }

        f32x4 acc[2][4];
        #pragma unroll
        for (int a = 0; a < 2; ++a)
            #pragma unroll
            for (int t = 0; t < 4; ++t) acc[a][t] = (f32x4)0.0f;

        #pragma unroll
        for (int tt = 0; tt < 4; ++tt) {
            const int t = tt * 16 + l15;
            bf16x8 btl[2], bwr[2], bwi[2];
            #pragma unroll
            for (int kk = 0; kk < 2; ++kk) {
                const int j0 = kk * 32 + quad * 8;
                btl[kk] = *(const bf16x8*)(wreg + t * PLSTR_ + j0);
                bwr[kk] = *(const bf16x8*)(wreg + 4608 + t * PLSTR_ + j0);
                bwi[kk] = *(const bf16x8*)(wreg + 9216 + t * PLSTR_ + j0);
            }
            #pragma unroll
            for (int mt = 0; mt < 2; ++mt)
                #pragma unroll
                for (int kk = 0; kk < 2; ++kk) {
                    acc[mt][tt] = __builtin_amdgcn_mfma_f32_16x16x32_bf16(
                        xhi[mt][kk], btl[kk], acc[mt][tt], 0, 0, 0);
                    acc[mt][tt] = __builtin_amdgcn_mfma_f32_16x16x32_bf16(
                        xlo[mt][kk], btl[kk], acc[mt][tt], 0, 0, 0);
                    acc[mt][tt] = __builtin_amdgcn_mfma_f32_16x16x32_bf16(
                        sr8[mt][kk], bwr[kk], acc[mt][tt], 0, 0, 0);
                    acc[mt][tt] = __builtin_amdgcn_mfma_f32_16x16x32_bf16(
                        si8[mt][kk], bwi[kk], acc[mt][tt], 0, 0, 0);
                }
        }

        // store y with relu; lanes 0..15 -> consecutive t (64B segments)
        #pragma unroll
        for (int mt = 0; mt < 2; ++mt)
            #pragma unroll
            for (int tt = 0; tt < 4; ++tt)
                #pragma unroll
                for (int r = 0; r < 4; ++r) {
                    const int bc = colw + mt * 16 + quad * 4 + r;
                    const int b  = bhalf * 4 + (bc >> 5);
                    const int c  = bc & 31;
                    const int t  = tt * 16 + l15;
                    out[((size_t)(b * H_ + h)) * L_ + c * Q_ + t] =
                        fmaxf(acc[mt][tt][r], 0.0f);
                }
    }
}

extern "C" void kernel_launch(void* const* d_in, const int* in_sizes, int n_in,
                              void* d_out, int out_size, void* d_ws, size_t ws_size,
                              hipStream_t stream) {
    const float* x      = (const float*)d_in[0];
    const float* A_real = (const float*)d_in[1];
    const float* A_imag = (const float*)d_in[2];
    const float* Bmat   = (const float*)d_in[3];
    const float* Cmat   = (const float*)d_in[4];
    const float* inv_dt = (const float*)d_in[5];
    float* out = (float*)d_out;
    (void)d_ws; (void)ws_size;

    s4d_one<<<dim3(H_ * 2), dim3(256), 0, stream>>>(
        x, A_real, A_imag, Bmat, Cmat, inv_dt, out);
}